// Round 5
// baseline (320.699 us; speedup 1.0000x reference)
//
#include <hip/hip_runtime.h>

typedef unsigned short u16;
typedef __attribute__((ext_vector_type(4))) float f32x4;
typedef __attribute__((ext_vector_type(8))) short s16x8;
typedef __attribute__((ext_vector_type(8))) unsigned short u16x8;
typedef __attribute__((ext_vector_type(4))) unsigned short u16x4;

// round-to-nearest-even f32 -> bf16
__device__ __forceinline__ u16 f2b(float x) {
  union { float f; unsigned u; } v; v.f = x;
  unsigned r = v.u + 0x7fffu + ((v.u >> 16) & 1u);
  return (u16)(r >> 16);
}
__device__ __forceinline__ float b2f(u16 x) {
  union { unsigned u; float f; } v; v.u = ((unsigned)x) << 16;
  return v.f;
}

// ---------------- cast fp32 -> bf16, 3 inputs in one launch (grid.y selects) ----------------
__global__ __launch_bounds__(256) void cast3_f32_bf16(const float* __restrict__ s0,
                                                      const float* __restrict__ s1,
                                                      const float* __restrict__ s2,
                                                      u16* __restrict__ dst, long n4) {
  const float* src = (blockIdx.y == 0) ? s0 : ((blockIdx.y == 1) ? s1 : s2);
  long i = blockIdx.x * 256 + threadIdx.x;
  if (i >= n4) return;
  float4 f = ((const float4*)src)[i];
  u16x4 o;
  o.x = f2b(f.x); o.y = f2b(f.y); o.z = f2b(f.z); o.w = f2b(f.w);
  ((u16x4*)(dst + blockIdx.y * n4 * 4))[i] = o;
}

// ---------------- W[E,A] fp32 -> Wt[A,E] bf16, 3 weights in one launch ----------------
__global__ __launch_bounds__(256) void transpose_cast_w3(const float* __restrict__ w0,
                                                         const float* __restrict__ w1,
                                                         const float* __restrict__ w2,
                                                         u16* __restrict__ Wt, int E_, int A_) {
  __shared__ float tile[32][33];
  const float* W = (blockIdx.z == 0) ? w0 : ((blockIdx.z == 1) ? w1 : w2);
  u16* dst = Wt + (long)blockIdx.z * E_ * A_;
  int a0 = blockIdx.x * 32, e0 = blockIdx.y * 32;
  int tx = threadIdx.x & 31, ty = threadIdx.x >> 5;
  for (int i = ty; i < 32; i += 8) tile[i][tx] = W[(long)(e0 + i) * A_ + a0 + tx];
  __syncthreads();
  for (int i = ty; i < 32; i += 8) dst[(long)(a0 + i) * E_ + e0 + tx] = f2b(tile[tx][i]);
}

// ============================================================================================
// R5: occupancy-first GEMM. 4 waves (256 thr), BM=128 x BN=256, BK=32, ring-3 LDS = 72 KB
// -> 2 BLOCKS/CU (16 waves/CU, independent barrier domains per block). Rationale: R2-R4
// showed ~2200 cyc/k-tile of exposed stall at 1 block/CU regardless of schedule; m114/m97
// evidence says co-resident independent blocks hide it (37+43% pipe util at 3 blk/CU vs
// our 27+15% at 1 blk/CU).
//   C[M,N] = A[M,K]*B[N,K]^T * scale + bias.  Per wave: 128x64 out (acc 8x4 frags,
//   128 AGPR); per k-tile: 8 A-reads + 4 B-reads (b128) + 32 MFMA; ONE barrier.
// Ring-3: stage tile tt+2 each iter (6 GLD: A 2 + B 4, 4 KB each); vmcnt(6) at iter end
// guarantees tile tt+1 landed; never vmcnt(0) until the tail. WAR: stage slot (tt+2)%3 was
// last read at iter tt-1, >=1 barrier earlier. Reads can't hoist across the iter-end
// vmcnt ("memory" clobber).
// Swizzle (proven 0-conflict in R4): 64B rows, store chunk = chunk ^ ((row>>1)&3) via
// pre-swizzled global source (LDS dest linear, m104/m173); same XOR on ds_read.
// KSPLIT: blockIdx.z folds (z, khalf); A/B advance khalf*KLEN; fp32 partials to
// Cg + khalf*sKh (PV split-K to fill the machine: 256 -> 512 blocks).
// z==2 + VtG (proj): write output transposed into Vt via u16x4.
// ============================================================================================
template<bool OUT_BF16, bool KSPLIT>
__global__ __launch_bounds__(256, 2)
void gemm4w(const u16* __restrict__ Ag, const u16* __restrict__ Bg,
            const float* __restrict__ b0, const float* __restrict__ b1,
            const float* __restrict__ b2, void* __restrict__ Cg,
            int gn, int KLEN, int LDA, int LDB, int N, float scale,
            long sA, long sB, long sC, long sKh,
            u16* __restrict__ VtG, long vtB, int vtS) {
  __shared__ __align__(128) char ldsc[73728];  // 3 x 24 KB ring
  const int t = threadIdx.x;
  const int w = t >> 6, l = t & 63;

  // T1: XCD-aware swizzle (grid.x % 8 == 0 -> bijective). Consecutive ids share im.
  const int nwg = gridDim.x;
  const int Lb = blockIdx.x;
  const int chunk = nwg >> 3;
  const int id = (Lb & 7) * chunk + (Lb >> 3);
  const int im = id / gn, in = id % gn;
  const int m0 = im * 128, n0 = in * 256;
  int z = blockIdx.z, kh = 0;
  if (KSPLIT) { kh = z & 1; z >>= 1; }
  const float* bias = (z == 0) ? b0 : ((z == 1) ? b1 : b2);

  const u16* Ab = Ag + (long)z * sA + (long)m0 * LDA + (long)kh * KLEN;
  const u16* Bb = Bg + (long)z * sB + (long)n0 * LDB + (long)kh * KLEN;

  // staging: op = 64 rows x 64 B = 4 KB; thread t -> dest byte t*16, dest row t>>2,
  // dest chunk t&3; source chunk = (t&3) ^ ((row>>1)&3) = (t&3) ^ ((t>>3)&3).
  const long soA = (long)(t >> 2) * LDA + (long)(((t & 3) ^ ((t >> 3) & 3)) << 3);
  const long soB = (long)(t >> 2) * LDB + (long)(((t & 3) ^ ((t >> 3) & 3)) << 3);
  const int d16 = t * 16;

  // ds_read bases: desired chunk l>>4, stored at chunk ^ ((row>>1)&3); frag rows are
  // 16a + (l&15) so the XOR term is lane-constant (l>>1)&3.
  const int cbR = (((l >> 4) ^ ((l >> 1) & 3)) << 4);
  const int aB = ((l & 15) << 6) + cbR;                    // A region @ 0 (8 KB)
  const int bB = 8192 + (w << 12) + ((l & 15) << 6) + cbR; // B region @ 8 KB (16 KB)

  f32x4 acc[8][4] = {};
  s16x8 af[8], bf[4];
  const int NTt = KLEN >> 5;

#define GLD(SRC, DST)                                                                        \
  __builtin_amdgcn_global_load_lds(                                                         \
      (const __attribute__((address_space(1))) unsigned int*)(SRC),                         \
      (__attribute__((address_space(3))) unsigned int*)(DST), 16, 0, 0)

#define STG(TT, SBASE) do {                                                                  \
    const u16* _sa = Ab + ((long)(TT) << 5) + soA;                                           \
    GLD(_sa,                   ldsc + (SBASE) + d16);                                        \
    GLD(_sa + (long)64 * LDA,  ldsc + (SBASE) + 4096 + d16);                                 \
    const u16* _sv = Bb + ((long)(TT) << 5) + soB;                                           \
    GLD(_sv,                   ldsc + (SBASE) + 8192 + d16);                                 \
    GLD(_sv + (long)64 * LDB,  ldsc + (SBASE) + 12288 + d16);                                \
    GLD(_sv + (long)128 * LDB, ldsc + (SBASE) + 16384 + d16);                                \
    GLD(_sv + (long)192 * LDB, ldsc + (SBASE) + 20480 + d16);                                \
  } while (0)

  // prologue: tiles 0,1 -> slots 0,1 (12 ops); vmcnt(6): tile 0 landed.
  STG(0, 0);
  STG(1, 24576);
  asm volatile("s_waitcnt vmcnt(6)" ::: "memory");
  __builtin_amdgcn_s_barrier();

  int cb = 0, sb = 49152;  // current slot byte, stage slot byte ((tt+2)%3)
  for (int tt = 0; tt < NTt; ++tt) {
#pragma unroll
    for (int i = 0; i < 8; ++i) af[i] = *(const s16x8*)(ldsc + cb + aB + (i << 10));
#pragma unroll
    for (int j = 0; j < 4; ++j) bf[j] = *(const s16x8*)(ldsc + cb + bB + (j << 10));
    if (tt + 2 < NTt) STG(tt + 2, sb);
    __builtin_amdgcn_s_setprio(1);
#pragma unroll
    for (int i = 0; i < 8; ++i)
#pragma unroll
      for (int j = 0; j < 4; ++j)
        acc[i][j] = __builtin_amdgcn_mfma_f32_16x16x32_bf16(af[i], bf[j], acc[i][j], 0, 0, 0);
    __builtin_amdgcn_s_setprio(0);
    if (tt + 2 < NTt)      asm volatile("s_waitcnt vmcnt(6)" ::: "memory");
    else if (tt + 1 < NTt) asm volatile("s_waitcnt vmcnt(0)" ::: "memory");
    __builtin_amdgcn_s_barrier();
    cb += 24576; if (cb >= 73728) cb = 0;
    sb += 24576; if (sb >= 73728) sb = 0;
  }
#undef STG
#undef GLD

  // epilogue. 16x16 C/D frag: col = l&15, row = (l>>4)*4 + r (m89-verified).
  float bj[4];
#pragma unroll
  for (int j = 0; j < 4; ++j) {
    int col = n0 + w * 64 + j * 16 + (l & 15);
    bj[j] = bias ? bias[col] : 0.0f;
  }

  if (OUT_BF16 && VtG != nullptr && z == 2) {
    const int b = m0 / vtS, smod = m0 % vtS;
    u16* vbase = VtG + (long)b * vtB + smod + ((l >> 4) << 2);
#pragma unroll
    for (int i8 = 0; i8 < 8; ++i8)
#pragma unroll
      for (int j = 0; j < 4; ++j) {
        int col = n0 + w * 64 + j * 16 + (l & 15);
        u16x4 o;
#pragma unroll
        for (int r = 0; r < 4; ++r) o[r] = f2b(acc[i8][j][r] * scale + bj[j]);
        *(u16x4*)(vbase + (long)col * vtS + i8 * 16) = o;
      }
  } else {
    char* Cz = (char*)Cg;
    long rbase = (long)z * sC + (KSPLIT ? (long)kh * sKh : 0) +
                 (long)(m0 + ((l >> 4) << 2)) * N + n0 + w * 64 + (l & 15);
#pragma unroll
    for (int i8 = 0; i8 < 8; ++i8)
#pragma unroll
      for (int j = 0; j < 4; ++j)
#pragma unroll
        for (int r = 0; r < 4; ++r) {
          float v = acc[i8][j][r] * scale + bj[j];
          long ro = rbase + (long)(i8 * 16 + r) * N + j * 16;
          if (OUT_BF16) ((u16*)Cz)[ro] = f2b(v);
          else          ((float*)Cz)[ro] = v;
        }
  }
}

// ---------------- out = a + b (fp32, vec4) — combines PV split-K partials ----------------
__global__ __launch_bounds__(256) void add2_f32(const float* __restrict__ a,
                                                const float* __restrict__ b,
                                                float* __restrict__ o, long n4) {
  long i = blockIdx.x * 256 + threadIdx.x;
  if (i >= n4) return;
  float4 x = ((const float4*)a)[i];
  float4 y = ((const float4*)b)[i];
  float4 r; r.x = x.x + y.x; r.y = x.y + y.y; r.z = x.z + y.z; r.w = x.w + y.w;
  ((float4*)o)[i] = r;
}

// ---------------- row softmax: bf16 [rows,2048] -> bf16 probs ----------------
__device__ __forceinline__ float wred_max(float x) {
  for (int o = 32; o > 0; o >>= 1) x = fmaxf(x, __shfl_xor(x, o));
  return x;
}
__device__ __forceinline__ float wred_sum(float x) {
  for (int o = 32; o > 0; o >>= 1) x += __shfl_xor(x, o);
  return x;
}

__global__ __launch_bounds__(256) void softmax_rows_bf16(const u16* __restrict__ S,
                                                         u16* __restrict__ P, int ncols) {
  long row = blockIdx.x;
  const u16x8* s8 = (const u16x8*)(S + row * (long)ncols);
  int t = threadIdx.x;
  int wave = t >> 6, lane = t & 63;
  u16x8 a = s8[t];
  float f[8];
#pragma unroll
  for (int i = 0; i < 8; i++) f[i] = b2f(a[i]);
  float m = f[0];
#pragma unroll
  for (int i = 1; i < 8; i++) m = fmaxf(m, f[i]);
  m = wred_max(m);
  __shared__ float redm[4], reds[4];
  if (lane == 0) redm[wave] = m;
  __syncthreads();
  m = fmaxf(fmaxf(redm[0], redm[1]), fmaxf(redm[2], redm[3]));

  float e[8], s = 0.f;
#pragma unroll
  for (int i = 0; i < 8; i++) { e[i] = __expf(f[i] - m); s += e[i]; }
  s = wred_sum(s);
  if (lane == 0) reds[wave] = s;
  __syncthreads();
  s = reds[0] + reds[1] + reds[2] + reds[3];
  float inv = 1.0f / s;

  u16x8 o;
#pragma unroll
  for (int i = 0; i < 8; i++) o[i] = f2b(e[i] * inv);
  ((u16x8*)(P + row * (long)ncols))[t] = o;
}

extern "C" void kernel_launch(void* const* d_in, const int* in_sizes, int n_in,
                              void* d_out, int out_size, void* d_ws, size_t ws_size,
                              hipStream_t stream) {
  const float* query = (const float*)d_in[0];
  const float* key_  = (const float*)d_in[1];
  const float* value = (const float*)d_in[2];
  const float* Wq = (const float*)d_in[3];
  const float* bq = (const float*)d_in[4];
  const float* Wk = (const float*)d_in[5];
  const float* bk = (const float*)d_in[6];
  const float* Wv = (const float*)d_in[7];
  const float* bv = (const float*)d_in[8];

  constexpr int B = 4, S = 2048, E = 1024, A = 1024;
  constexpr long MB = 1024 * 1024;
  char* ws = (char*)d_ws;
  // layout (MiB): Qb 0-16, Kb 16-32, (free 32-48), Vt 48-64, P 64-96, Sc 96-128,
  // Xq(transient) 96-144 (consumed by proj before Sc written), Wt 144-150.
  // PV partials reuse DEAD regions: kh=0 -> 0-32 (Qb/Kb dead), kh=1 -> 96-128 (Sc dead).
  u16* Qb  = (u16*)(ws + 0 * MB);
  u16* Kb  = (u16*)(ws + 16 * MB);
  u16* Vt  = (u16*)(ws + 48 * MB);
  u16* P   = (u16*)(ws + 64 * MB);
  u16* Sc  = (u16*)(ws + 96 * MB);
  u16* Xq  = (u16*)(ws + 96 * MB);  // z-stride 8M elems (16 MB)
  u16* WqT = (u16*)(ws + 144 * MB); // z-stride 1M elems (2 MB)
  float* Cp0 = (float*)(ws + 0 * MB);   // PV partial kh=0 (32 MB)

  const long n = (long)B * S * E;   // 8M activation elements per tensor
  const long n4 = n / 4;
  dim3 blk(256);

  // 1) cast q/k/v fp32 -> bf16 (one launch)
  cast3_f32_bf16<<<dim3(n4 / 256, 3), blk, 0, stream>>>(query, key_, value, Xq, n4);

  // 2) W[E,A] -> Wt[A,E] bf16, all three (one launch)
  transpose_cast_w3<<<dim3(A / 32, E / 32, 3), blk, 0, stream>>>(Wq, Wk, Wv, WqT, E, A);

  // 3) merged QKV projections: z=0->Qb, z=1->Kb, z=2->Vt (transposed u16x4 scatter).
  //    M=8192 (im 64), N=1024 (gn 4) -> 256 blocks x 3 z = 768 (1.5 fills of 512 slots).
  gemm4w<true, false><<<dim3(256, 1, 3), blk, 0, stream>>>(
      Xq, WqT, bq, bk, bv, Qb, 4, E, E, E, A, 1.0f,
      (long)8 * MB, (long)1 * MB, (long)8 * MB, 0,
      Vt, (long)A * S, S);

  // 4) scores = Q K^T / sqrt(A): M=N=2048 (im 16, gn 8) -> 128 x 4 z = 512 (exact fill).
  gemm4w<true, false><<<dim3(128, 1, 4), blk, 0, stream>>>(
      Qb, Kb, nullptr, nullptr, nullptr, Sc, 8, A, A, A, S, 0.03125f,
      (long)S * A, (long)S * A, (long)S * S, 0, nullptr, 0, 1);

  // 5) softmax rows (bf16 in, bf16 out)
  softmax_rows_bf16<<<dim3(B * S), blk, 0, stream>>>(Sc, P, S);

  // 6) out = P V, split-K: A=P[S,S] (LDA=S), B=Vt[A,S] (LDB=S), KLEN=1024 per half.
  //    M=2048 (im 16), N=1024 (gn 4) -> 64 x 8 z' = 512 blocks (exact fill).
  //    kh=0 -> Cp0 (ws+0), kh=1 -> ws+96MB (sKh = 24M floats).
  gemm4w<false, true><<<dim3(64, 1, 8), blk, 0, stream>>>(
      P, Vt, nullptr, nullptr, nullptr, Cp0, 4, 1024, S, S, A, 1.0f,
      (long)S * S, (long)S * A, (long)S * A, (long)24 * MB, nullptr, 0, 1);

  // 7) combine partials -> fp32 d_out
  const long o4 = (long)B * S * A / 4;  // 2M float4
  add2_f32<<<dim3(o4 / 256), blk, 0, stream>>>(Cp0, (const float*)(ws + 96 * MB),
                                               (float*)d_out, o4);
}